// Round 7
// baseline (4546.463 us; speedup 1.0000x reference)
//
#include <hip/hip_runtime.h>

// ---------------------------------------------------------------------------
// ManualLSTM: B=32, S=512, H=1024.
//   Phase A: xg = bf16(x) @ bf16(Wi)  -> bf16 [16384][4096]  (bias in phase B)
//   Phase B (R13 = R10 with direct-to-register A-frags): persistent
//     recurrence, 4 groups x 64 blocks. Group g owns batches 8g..8g+7 + full
//     gate dim; block m owns hidden cols m*16..+16 (64 gate cols).
//     - Wh B-frags pinned in VGPRs (asm "+v" tie; R10-validated).
//     - A-frags loaded DIRECTLY from the ring into registers (R8-validated
//       LD8/FM8 pattern: 32 independent dwordx4 loads issued up-front, MFMA
//       overlapped) -- no h LDS image, no staging writes, one barrier fewer.
//       L1 + coalescer merge the 2x lane duplication and 4-wave sharing.
//     - h exchange via NEVER-REUSED ring (512 slots x 4 groups x 16KB,
//       overlays dead xb region). Producers: shfl-packed 8B agent-scope
//       atomic stores. Consumers: PLAIN loads of virgin addresses (no stale
//       L1/L2 possible; R8/R9/R10-validated).
//     - Drain: ring store first, out[] second, s_waitcnt vmcnt(1) waits the
//       ring store only; barrier; relaxed agent flag (R10-validated).
//     - LDS: gates only (4.2KB).
// ---------------------------------------------------------------------------

typedef __attribute__((ext_vector_type(4))) float f32x4_t;
typedef __attribute__((ext_vector_type(8))) short bf16x8_t;
typedef unsigned long long ull_t;

#define HID   1024
#define SLEN  512
#define NGATE 4096

// ws layout (bytes)
#define XG_OFF    0ULL                      // 16384*4096*2 = 134217728
#define RING_OFF  134217728ULL              // 512*4*16384  = 33554432 (old xb)
#define WIT_OFF   167772160ULL              // 4096*1024*2  = 8388608
#define WHT_OFF   176160768ULL              // 4096*1024*2  = 8388608
#define FLAGS_OFF 184680448ULL              // 256 packed 4B flags = 1024B
// xb (phase-A bf16 x) shares the RING region: gemm_xg reads it fully before
// lstm_persistent writes the ring (same stream, sequential dispatches).
#define XB_OFF    RING_OFF

#define NBLK_B      256                     // 4 groups x 64 blocks
#define SLOT_SHORTS 32768                   // 4 groups * 8192 shorts = 64KB/slot

__device__ __forceinline__ unsigned short f2bf(float f) {
  unsigned u = __float_as_uint(f);
  u += 0x7fffu + ((u >> 16) & 1u);          // round-nearest-even
  return (unsigned short)(u >> 16);
}
__device__ __forceinline__ float bf2f(unsigned short u) {
  return __uint_as_float(((unsigned)u) << 16);
}
__device__ __forceinline__ float fast_rcp(float x) { return __builtin_amdgcn_rcpf(x); }
__device__ __forceinline__ float sigmoid_f(float x) { return fast_rcp(1.f + __expf(-x)); }
__device__ __forceinline__ float tanh_f(float x) { return 1.f - 2.f * fast_rcp(1.f + __expf(2.f * x)); }

// ---------------------------------------------------------------- converters
__global__ __launch_bounds__(256) void conv_x_bf16(const float* __restrict__ in,
                                                   unsigned short* __restrict__ out) {
  size_t i = (size_t)blockIdx.x * 256 + threadIdx.x;
  const float4* p = (const float4*)in;
  float4 v = p[i];
  ushort4 o;
  o.x = f2bf(v.x); o.y = f2bf(v.y); o.z = f2bf(v.z); o.w = f2bf(v.w);
  ((ushort4*)out)[i] = o;
}

// in: fp32 [1024][4096]  -> out: bf16 [4096][1024]  (out[n][k] = in[k][n])
__global__ void transpose_w_bf16(const float* __restrict__ in,
                                 unsigned short* __restrict__ out) {
  __shared__ float tile[32][33];
  int tx = threadIdx.x, ty = threadIdx.y;        // block (32, 8)
  int n0 = blockIdx.x * 32, k0 = blockIdx.y * 32;
  #pragma unroll
  for (int i = 0; i < 4; i++)
    tile[ty + 8 * i][tx] = in[(size_t)(k0 + ty + 8 * i) * NGATE + n0 + tx];
  __syncthreads();
  #pragma unroll
  for (int i = 0; i < 4; i++)
    out[(size_t)(n0 + ty + 8 * i) * HID + k0 + tx] = f2bf(tile[tx][ty + 8 * i]);
}

__global__ void init_ws(unsigned* __restrict__ flags) {
  int i = threadIdx.x;                      // 256 packed flags
  flags[i] = 0u;
}

// ---------------------------------------------------------------- Phase A
// C[16384][4096] bf16 = A[16384][1024] bf16  x  BT[4096][1024] bf16
__global__ __launch_bounds__(256) void gemm_xg(const unsigned short* __restrict__ A,
                                               const unsigned short* __restrict__ BT,
                                               unsigned short* __restrict__ C) {
  extern __shared__ char smem[];
  char* As = smem;                 // 128 rows * 80B (32 bf16 + 16B pad)
  char* Bs = smem + 10240;
  const int tid = threadIdx.x;
  const int lane = tid & 63, w = tid >> 6, q = lane >> 4, l16 = lane & 15;
  const int wm = w & 1, wn = w >> 1;
  const size_t m0 = (size_t)blockIdx.y * 128, n0 = (size_t)blockIdx.x * 128;

  f32x4_t acc[4][4];
  #pragma unroll
  for (int i = 0; i < 4; i++)
    #pragma unroll
    for (int j = 0; j < 4; j++) acc[i][j] = (f32x4_t){0.f, 0.f, 0.f, 0.f};

  for (int kk = 0; kk < 32; kk++) {
    const int k0 = kk * 32;
    #pragma unroll
    for (int h = 0; h < 2; h++) {
      int idx = tid + h * 256;              // 0..511
      int r = idx >> 2, ch = idx & 3;
      uint4 va = *(const uint4*)((const char*)A + ((m0 + r) * HID + k0) * 2 + ch * 16);
      *(uint4*)(As + r * 80 + ch * 16) = va;
      uint4 vb = *(const uint4*)((const char*)BT + ((n0 + r) * HID + k0) * 2 + ch * 16);
      *(uint4*)(Bs + r * 80 + ch * 16) = vb;
    }
    __syncthreads();
    bf16x8_t af[4], bf[4];
    #pragma unroll
    for (int mt = 0; mt < 4; mt++)
      af[mt] = *(const bf16x8_t*)(As + (wm * 64 + mt * 16 + l16) * 80 + q * 16);
    #pragma unroll
    for (int nt = 0; nt < 4; nt++)
      bf[nt] = *(const bf16x8_t*)(Bs + (wn * 64 + nt * 16 + l16) * 80 + q * 16);
    #pragma unroll
    for (int mt = 0; mt < 4; mt++)
      #pragma unroll
      for (int nt = 0; nt < 4; nt++)
        acc[mt][nt] = __builtin_amdgcn_mfma_f32_16x16x32_bf16(af[mt], bf[nt], acc[mt][nt], 0, 0, 0);
    __syncthreads();
  }

  // epilogue: stage C tile (bf16 [128][136]) through LDS for coalesced stores
  unsigned short* cst = (unsigned short*)smem;
  #pragma unroll
  for (int mt = 0; mt < 4; mt++)
    #pragma unroll
    for (int nt = 0; nt < 4; nt++)
      #pragma unroll
      for (int r = 0; r < 4; r++) {
        int m = wm * 64 + mt * 16 + q * 4 + r;
        int n = wn * 64 + nt * 16 + l16;
        cst[m * 136 + n] = f2bf(acc[mt][nt][r]);
      }
  __syncthreads();
  #pragma unroll
  for (int i = 0; i < 8; i++) {
    int idx = tid + i * 256;                // < 2048
    int row = idx >> 4, ch = idx & 15;
    uint4 v = *(const uint4*)((const char*)cst + row * 272 + ch * 16);
    *(uint4*)((char*)C + ((m0 + row) * NGATE + n0) * 2 + ch * 16) = v;
  }
}

// ---------------------------------------------------------------- Phase B
// 4 groups x 64 blocks x 256 threads. Group = 8 batches, full gate dim.
// Block m: hidden cols m*16..+16 => local gate cols n = G*16+j, G=0..3.
#define LD8(dst, base_kk)                                                     \
  _Pragma("unroll")                                                           \
  for (int i_ = 0; i_ < 8; i_++)                                              \
    dst[i_] = *(const bf16x8_t*)(ab + (base_kk) * 64 + i_ * 64);

#define FM8(src, base_kk)                                                     \
  _Pragma("unroll")                                                           \
  for (int i_ = 0; i_ < 4; i_++) {                                            \
    acc0 = __builtin_amdgcn_mfma_f32_16x16x32_bf16(src[2 * i_],               \
             bfr[(base_kk) + 2 * i_], acc0, 0, 0, 0);                         \
    acc1 = __builtin_amdgcn_mfma_f32_16x16x32_bf16(src[2 * i_ + 1],           \
             bfr[(base_kk) + 2 * i_ + 1], acc1, 0, 0, 0);                     \
  }

__global__ __launch_bounds__(256, 1) void lstm_persistent(
    const unsigned short* __restrict__ xg,   // [16384][4096] bf16
    const unsigned short* __restrict__ whT,  // [4096][1024] bf16
    const float* __restrict__ bias,          // [4096]
    float* __restrict__ out,                 // [32][512][1024]
    unsigned short* ring,                    // 512 slots x 4 groups x [8][1024] bf16
    unsigned* flags) {                       // 256 packed 4B, group-major
  __shared__ float gates[16 * 65];           // [16][65] f32 (rows 8-15 dup)

  const int tid = threadIdx.x;
  const int lane = tid & 63, wv = tid >> 6, q = lane >> 4, l16 = lane & 15;
  const int g = blockIdx.x >> 6;                   // group 0..3
  const int m = blockIdx.x & 63;                   // member 0..63
  const int b_l = tid >> 4, j_l = tid & 15;        // EW mapping (tid<128)

  // pin Wh B-fragments in VGPRs: wave wv owns gate cols wv*1024 + m*16 + l16.
  // Loaded once; volatile asm "+v" ties block the R8 failure mode (compiler
  // sinking the loads into the t-loop). R10-validated.
  bf16x8_t bfr[32];
  {
    const char* wrow = (const char*)whT +
        ((size_t)(wv * 1024 + m * 16 + l16) * HID) * 2 + q * 16;
    #pragma unroll
    for (int kk = 0; kk < 32; kk++)
      bfr[kk] = *(const bf16x8_t*)(wrow + kk * 64);
    #pragma unroll
    for (int kk = 0; kk < 32; kk++)
      asm volatile("" : "+v"(bfr[kk]));
  }
  float bsr[4];
  #pragma unroll
  for (int G = 0; G < 4; G++) bsr[G] = bias[G * 1024 + m * 16 + j_l];
  float c_st = 0.f;
  unsigned short* ring_g = ring + (size_t)g * 8192;       // 16KB group image
  unsigned* fl_g = flags + g * 64;                        // packed 4B flags
  const int a_off = (l16 & 7) * 2048 + q * 16;            // bytes in [8][2048B]

  for (int t = 0; t < SLEN; t++) {
    // xg prefetch (no h dependency) — overlaps the flag wait
    unsigned short xgv[4];
    if (tid < 128) {
      const unsigned short* p =
          xg + ((size_t)(g * 8 + b_l) * 512 + t) * 4096 + m * 16 + j_l;
      xgv[0] = p[0]; xgv[1] = p[1024]; xgv[2] = p[2048]; xgv[3] = p[3072];
    }
    f32x4_t acc0 = (f32x4_t){0.f, 0.f, 0.f, 0.f};
    f32x4_t acc1 = (f32x4_t){0.f, 0.f, 0.f, 0.f};
    if (t > 0) {
      if (tid < 64) {
        const unsigned* fp = fl_g + tid;     // 64 lanes = one 256B load
        while (__hip_atomic_load(fp, __ATOMIC_RELAXED, __HIP_MEMORY_SCOPE_AGENT) < (unsigned)t)
          __builtin_amdgcn_s_sleep(1);
      }
      __syncthreads();
      asm volatile("" ::: "memory");
      // A-frags DIRECTLY from ring slot t-1 into registers (plain loads of
      // virgin addresses -> no stale cache copy; producers wrote LLC). All
      // 32 independent loads issue up-front; MFMA overlaps the tail.
      const char* ab = (const char*)(ring_g + (size_t)(t - 1) * SLOT_SHORTS) + a_off;
      bf16x8_t af0[8], af1[8], af2[8], af3[8];
      LD8(af0, 0);  LD8(af1, 8);
      FM8(af0, 0);  LD8(af2, 16);
      FM8(af1, 8);  LD8(af3, 24);
      FM8(af2, 16); FM8(af3, 24);
    }
    #pragma unroll
    for (int r = 0; r < 4; r++) {
      int bb = q * 4 + r;                          // rows 8-15 are duplicates
      gates[bb * 65 + wv * 16 + l16] = acc0[r] + acc1[r];
    }
    __syncthreads();

    // elementwise: 128 threads own (b_l, j_l)
    if (tid < 128) {
      float gi = gates[b_l * 65 + j_l]      + bsr[0] + bf2f(xgv[0]);
      float gf = gates[b_l * 65 + 16 + j_l] + bsr[1] + bf2f(xgv[1]);
      float gg = gates[b_l * 65 + 32 + j_l] + bsr[2] + bf2f(xgv[2]);
      float go = gates[b_l * 65 + 48 + j_l] + bsr[3] + bf2f(xgv[3]);
      float i_s = sigmoid_f(gi), f_s = sigmoid_f(gf);
      float g_t = tanh_f(gg), o_s = sigmoid_f(go);
      c_st = f_s * c_st + i_s * g_t;
      float h = o_s * tanh_f(c_st);
      // pack 4 cols into 8B via two shuffles; lanes j%4==0 store LLC-direct.
      // Ring store issued FIRST (oldest) so vmcnt(1) below waits only it.
      unsigned short hb = f2bf(h);
      unsigned other = __shfl_xor((unsigned)hb, 1);
      unsigned u = ((unsigned)hb & 0xffffu) | (other << 16);   // cols j, j+1
      unsigned u2 = __shfl_xor(u, 2);                          // cols j+2, j+3
      if ((j_l & 3) == 0) {
        ull_t v8 = (ull_t)u | ((ull_t)u2 << 32);
        ull_t* dst = (ull_t*)(ring_g + (size_t)t * SLOT_SHORTS +
                              b_l * 1024 + m * 16 + j_l);
        __hip_atomic_store(dst, v8, __ATOMIC_RELAXED, __HIP_MEMORY_SCOPE_AGENT);
      }
      asm volatile("" ::: "memory");   // keep out-store AFTER ring store
      out[((size_t)(g * 8 + b_l) * 512 + t) * 1024 + m * 16 + j_l] = h;
    }
    // drain the ring store only (oldest); out[] HBM ack stays off the path
    asm volatile("s_waitcnt vmcnt(1)" ::: "memory");
    __syncthreads();
    if (tid == 0)
      __hip_atomic_store(fl_g + m, (unsigned)(t + 1),
                         __ATOMIC_RELAXED, __HIP_MEMORY_SCOPE_AGENT);
  }
}

// ---------------------------------------------------------------- launcher
extern "C" void kernel_launch(void* const* d_in, const int* in_sizes, int n_in,
                              void* d_out, int out_size, void* d_ws, size_t ws_size,
                              hipStream_t stream) {
  const float* x    = (const float*)d_in[0];   // [32,512,1024]
  const float* wi   = (const float*)d_in[1];   // [1024,4096]
  const float* wh   = (const float*)d_in[2];   // [1024,4096]
  const float* bias = (const float*)d_in[3];   // [4096]
  float* out = (float*)d_out;

  char* ws = (char*)d_ws;
  unsigned short* xg   = (unsigned short*)(ws + XG_OFF);
  unsigned short* xb   = (unsigned short*)(ws + XB_OFF);   // dead after gemm_xg
  unsigned short* ring = (unsigned short*)(ws + RING_OFF); // overlays xb
  unsigned short* wiT  = (unsigned short*)(ws + WIT_OFF);
  unsigned short* whT  = (unsigned short*)(ws + WHT_OFF);
  unsigned* flags      = (unsigned*)(ws + FLAGS_OFF);

  conv_x_bf16<<<16384, 256, 0, stream>>>(x, xb);
  transpose_w_bf16<<<dim3(128, 32), dim3(32, 8), 0, stream>>>(wi, wiT);
  transpose_w_bf16<<<dim3(128, 32), dim3(32, 8), 0, stream>>>(wh, whT);
  init_ws<<<1, 256, 0, stream>>>(flags);
  gemm_xg<<<dim3(32, 128), 256, 34816, stream>>>(xb, wiT, xg);
  lstm_persistent<<<NBLK_B, 256, 0, stream>>>(xg, whT, bias, out, ring, flags);
}

// Round 8
// 2167.548 us; speedup vs baseline: 2.0975x; 2.0975x over previous
//
#include <hip/hip_runtime.h>

// ---------------------------------------------------------------------------
// ManualLSTM: B=32, S=512, H=1024.
//   Phase A: xg = bf16(x) @ bf16(Wi)  -> bf16 [16384][4096]  (bias in phase B)
//   Phase B (R14 = R10 exact + packed 4B flags): persistent recurrence,
//     4 groups x 64 blocks. Group g owns batches 8g..8g+7 + full gate dim;
//     block m owns hidden cols m*16..+16 (64 gate cols).
//     - Wh B-frags pinned in VGPRs (asm "+v" tie; R10-validated). K-loop =
//       32 ds_read_b128 (A only) + 32 MFMA.
//     - h exchange via NEVER-REUSED ring (512 slots x 4 groups x 16KB,
//       overlays dead xb region). Producers: shfl-packed 8B agent-scope
//       atomic stores. Consumers: ONE cooperative coalesced dwordx4 gather
//       into LDS, then ds_read redistribution (R9/R10-validated transport;
//       R13 proved per-wave direct-reg loads storm the LLC, 2.6x slower).
//     - Flags packed at 4B stride: 64-flag poll = one 256B coalesced load
//       (4 lines; passed correctness in R11/R13).
//     - Drain: ring store issued first, out[] second, s_waitcnt vmcnt(1)
//       waits only the ring store; barrier; relaxed agent flag
//       (R10-validated).
// ---------------------------------------------------------------------------

typedef __attribute__((ext_vector_type(4))) float f32x4_t;
typedef __attribute__((ext_vector_type(8))) short bf16x8_t;
typedef unsigned long long ull_t;

#define HID   1024
#define SLEN  512
#define NGATE 4096

// ws layout (bytes)
#define XG_OFF    0ULL                      // 16384*4096*2 = 134217728
#define RING_OFF  134217728ULL              // 512*4*16384  = 33554432 (old xb)
#define WIT_OFF   167772160ULL              // 4096*1024*2  = 8388608
#define WHT_OFF   176160768ULL              // 4096*1024*2  = 8388608
#define FLAGS_OFF 184680448ULL              // 256 packed 4B flags = 1024B
// xb (phase-A bf16 x) shares the RING region: gemm_xg reads it fully before
// lstm_persistent writes the ring (same stream, sequential dispatches).
#define XB_OFF    RING_OFF

#define NBLK_B      256                     // 4 groups x 64 blocks
#define SLOT_SHORTS 32768                   // 4 groups * 8192 shorts = 64KB/slot

__device__ __forceinline__ unsigned short f2bf(float f) {
  unsigned u = __float_as_uint(f);
  u += 0x7fffu + ((u >> 16) & 1u);          // round-nearest-even
  return (unsigned short)(u >> 16);
}
__device__ __forceinline__ float bf2f(unsigned short u) {
  return __uint_as_float(((unsigned)u) << 16);
}
__device__ __forceinline__ float fast_rcp(float x) { return __builtin_amdgcn_rcpf(x); }
__device__ __forceinline__ float sigmoid_f(float x) { return fast_rcp(1.f + __expf(-x)); }
__device__ __forceinline__ float tanh_f(float x) { return 1.f - 2.f * fast_rcp(1.f + __expf(2.f * x)); }

// ---------------------------------------------------------------- converters
__global__ __launch_bounds__(256) void conv_x_bf16(const float* __restrict__ in,
                                                   unsigned short* __restrict__ out) {
  size_t i = (size_t)blockIdx.x * 256 + threadIdx.x;
  const float4* p = (const float4*)in;
  float4 v = p[i];
  ushort4 o;
  o.x = f2bf(v.x); o.y = f2bf(v.y); o.z = f2bf(v.z); o.w = f2bf(v.w);
  ((ushort4*)out)[i] = o;
}

// in: fp32 [1024][4096]  -> out: bf16 [4096][1024]  (out[n][k] = in[k][n])
__global__ void transpose_w_bf16(const float* __restrict__ in,
                                 unsigned short* __restrict__ out) {
  __shared__ float tile[32][33];
  int tx = threadIdx.x, ty = threadIdx.y;        // block (32, 8)
  int n0 = blockIdx.x * 32, k0 = blockIdx.y * 32;
  #pragma unroll
  for (int i = 0; i < 4; i++)
    tile[ty + 8 * i][tx] = in[(size_t)(k0 + ty + 8 * i) * NGATE + n0 + tx];
  __syncthreads();
  #pragma unroll
  for (int i = 0; i < 4; i++)
    out[(size_t)(n0 + ty + 8 * i) * HID + k0 + tx] = f2bf(tile[tx][ty + 8 * i]);
}

__global__ void init_ws(unsigned* __restrict__ flags) {
  int i = threadIdx.x;                      // 256 packed flags
  flags[i] = 0u;
}

// ---------------------------------------------------------------- Phase A
// C[16384][4096] bf16 = A[16384][1024] bf16  x  BT[4096][1024] bf16
__global__ __launch_bounds__(256) void gemm_xg(const unsigned short* __restrict__ A,
                                               const unsigned short* __restrict__ BT,
                                               unsigned short* __restrict__ C) {
  extern __shared__ char smem[];
  char* As = smem;                 // 128 rows * 80B (32 bf16 + 16B pad)
  char* Bs = smem + 10240;
  const int tid = threadIdx.x;
  const int lane = tid & 63, w = tid >> 6, q = lane >> 4, l16 = lane & 15;
  const int wm = w & 1, wn = w >> 1;
  const size_t m0 = (size_t)blockIdx.y * 128, n0 = (size_t)blockIdx.x * 128;

  f32x4_t acc[4][4];
  #pragma unroll
  for (int i = 0; i < 4; i++)
    #pragma unroll
    for (int j = 0; j < 4; j++) acc[i][j] = (f32x4_t){0.f, 0.f, 0.f, 0.f};

  for (int kk = 0; kk < 32; kk++) {
    const int k0 = kk * 32;
    #pragma unroll
    for (int h = 0; h < 2; h++) {
      int idx = tid + h * 256;              // 0..511
      int r = idx >> 2, ch = idx & 3;
      uint4 va = *(const uint4*)((const char*)A + ((m0 + r) * HID + k0) * 2 + ch * 16);
      *(uint4*)(As + r * 80 + ch * 16) = va;
      uint4 vb = *(const uint4*)((const char*)BT + ((n0 + r) * HID + k0) * 2 + ch * 16);
      *(uint4*)(Bs + r * 80 + ch * 16) = vb;
    }
    __syncthreads();
    bf16x8_t af[4], bf[4];
    #pragma unroll
    for (int mt = 0; mt < 4; mt++)
      af[mt] = *(const bf16x8_t*)(As + (wm * 64 + mt * 16 + l16) * 80 + q * 16);
    #pragma unroll
    for (int nt = 0; nt < 4; nt++)
      bf[nt] = *(const bf16x8_t*)(Bs + (wn * 64 + nt * 16 + l16) * 80 + q * 16);
    #pragma unroll
    for (int mt = 0; mt < 4; mt++)
      #pragma unroll
      for (int nt = 0; nt < 4; nt++)
        acc[mt][nt] = __builtin_amdgcn_mfma_f32_16x16x32_bf16(af[mt], bf[nt], acc[mt][nt], 0, 0, 0);
    __syncthreads();
  }

  // epilogue: stage C tile (bf16 [128][136]) through LDS for coalesced stores
  unsigned short* cst = (unsigned short*)smem;
  #pragma unroll
  for (int mt = 0; mt < 4; mt++)
    #pragma unroll
    for (int nt = 0; nt < 4; nt++)
      #pragma unroll
      for (int r = 0; r < 4; r++) {
        int m = wm * 64 + mt * 16 + q * 4 + r;
        int n = wn * 64 + nt * 16 + l16;
        cst[m * 136 + n] = f2bf(acc[mt][nt][r]);
      }
  __syncthreads();
  #pragma unroll
  for (int i = 0; i < 8; i++) {
    int idx = tid + i * 256;                // < 2048
    int row = idx >> 4, ch = idx & 15;
    uint4 v = *(const uint4*)((const char*)cst + row * 272 + ch * 16);
    *(uint4*)((char*)C + ((m0 + row) * NGATE + n0) * 2 + ch * 16) = v;
  }
}

// ---------------------------------------------------------------- Phase B
// 4 groups x 64 blocks x 256 threads. Group = 8 batches, full gate dim.
// Block m: hidden cols m*16..+16 => local gate cols n = G*16+j, G=0..3.
__global__ __launch_bounds__(256, 1) void lstm_persistent(
    const unsigned short* __restrict__ xg,   // [16384][4096] bf16
    const unsigned short* __restrict__ whT,  // [4096][1024] bf16
    const float* __restrict__ bias,          // [4096]
    float* __restrict__ out,                 // [32][512][1024]
    unsigned short* ring,                    // 512 slots x 4 groups x [8][1024] bf16
    unsigned* flags) {                       // 256 packed 4B, group-major
  __shared__ __align__(16) char h_lds[8 * 2064];   // [8 rows b][2048B k] +16B pad
  __shared__ float gates[16 * 65];                 // [16][65] f32 (rows 8-15 dup)

  const int tid = threadIdx.x;
  const int lane = tid & 63, wv = tid >> 6, q = lane >> 4, l16 = lane & 15;
  const int g = blockIdx.x >> 6;                   // group 0..3
  const int m = blockIdx.x & 63;                   // member 0..63
  const int b_l = tid >> 4, j_l = tid & 15;        // EW mapping (tid<128)

  // pin Wh B-fragments in VGPRs: wave wv owns gate cols wv*1024 + m*16 + l16.
  // Loaded once; volatile asm "+v" ties block the R8 failure mode (compiler
  // sinking the loads into the t-loop). R10-validated.
  bf16x8_t bfr[32];
  {
    const char* wrow = (const char*)whT +
        ((size_t)(wv * 1024 + m * 16 + l16) * HID) * 2 + q * 16;
    #pragma unroll
    for (int kk = 0; kk < 32; kk++)
      bfr[kk] = *(const bf16x8_t*)(wrow + kk * 64);
    #pragma unroll
    for (int kk = 0; kk < 32; kk++)
      asm volatile("" : "+v"(bfr[kk]));
  }
  float bsr[4];
  #pragma unroll
  for (int G = 0; G < 4; G++) bsr[G] = bias[G * 1024 + m * 16 + j_l];
  float c_st = 0.f;
  const char* arow = h_lds + (l16 & 7) * 2064 + q * 16;   // rows 8-15 mirror 0-7
  unsigned short* ring_g = ring + (size_t)g * 8192;       // 16KB group image
  unsigned* fl_g = flags + g * 64;                        // packed 4B flags

  for (int t = 0; t < SLEN; t++) {
    // xg prefetch (no h dependency) — overlaps the flag wait
    unsigned short xgv[4];
    if (tid < 128) {
      const unsigned short* p =
          xg + ((size_t)(g * 8 + b_l) * 512 + t) * 4096 + m * 16 + j_l;
      xgv[0] = p[0]; xgv[1] = p[1024]; xgv[2] = p[2048]; xgv[3] = p[3072];
    }
    if (t > 0) {
      if (tid < 64) {
        const unsigned* fp = fl_g + tid;     // 64 lanes = one 256B load
        while (__hip_atomic_load(fp, __ATOMIC_RELAXED, __HIP_MEMORY_SCOPE_AGENT) < (unsigned)t)
          __builtin_amdgcn_s_sleep(1);
      }
      __syncthreads();
      asm volatile("" ::: "memory");
      // gather group h image from ring slot t-1 with PLAIN coalesced dwordx4
      // (virgin addresses -> no stale L1/L2; producers wrote LLC; lane-
      //  contiguous 16B chunks -> 1KB/instruction, line-based, L2-shared)
      {
        const char* src = (const char*)(ring_g + (size_t)(t - 1) * SLOT_SHORTS);
        uint4 v0 = *(const uint4*)(src + tid * 16);
        uint4 v1 = *(const uint4*)(src + tid * 16 + 4096);
        uint4 v2 = *(const uint4*)(src + tid * 16 + 8192);
        uint4 v3 = *(const uint4*)(src + tid * 16 + 12288);
        int c0 = tid, c1 = tid + 256, c2 = tid + 512, c3 = tid + 768;
        *(uint4*)(h_lds + (c0 >> 7) * 2064 + (c0 & 127) * 16) = v0;
        *(uint4*)(h_lds + (c1 >> 7) * 2064 + (c1 & 127) * 16) = v1;
        *(uint4*)(h_lds + (c2 >> 7) * 2064 + (c2 & 127) * 16) = v2;
        *(uint4*)(h_lds + (c3 >> 7) * 2064 + (c3 & 127) * 16) = v3;
      }
    }
    __syncthreads();

    // gates[b][n] = sum_k h[b][k] * Wslice[k][n]; wave wv = N-tile wv.
    // B comes from pinned VGPRs; only A is read from LDS (32 ds_read_b128).
    f32x4_t acc0 = (f32x4_t){0.f, 0.f, 0.f, 0.f};
    f32x4_t acc1 = (f32x4_t){0.f, 0.f, 0.f, 0.f};
    if (t > 0) {
      #pragma unroll
      for (int kk = 0; kk < 32; kk += 2) {
        bf16x8_t a0 = *(const bf16x8_t*)(arow + kk * 64);
        bf16x8_t a1 = *(const bf16x8_t*)(arow + kk * 64 + 64);
        acc0 = __builtin_amdgcn_mfma_f32_16x16x32_bf16(a0, bfr[kk], acc0, 0, 0, 0);
        acc1 = __builtin_amdgcn_mfma_f32_16x16x32_bf16(a1, bfr[kk + 1], acc1, 0, 0, 0);
      }
    }
    #pragma unroll
    for (int r = 0; r < 4; r++) {
      int bb = q * 4 + r;                          // rows 8-15 are duplicates
      gates[bb * 65 + wv * 16 + l16] = acc0[r] + acc1[r];
    }
    __syncthreads();

    // elementwise: 128 threads own (b_l, j_l)
    if (tid < 128) {
      float gi = gates[b_l * 65 + j_l]      + bsr[0] + bf2f(xgv[0]);
      float gf = gates[b_l * 65 + 16 + j_l] + bsr[1] + bf2f(xgv[1]);
      float gg = gates[b_l * 65 + 32 + j_l] + bsr[2] + bf2f(xgv[2]);
      float go = gates[b_l * 65 + 48 + j_l] + bsr[3] + bf2f(xgv[3]);
      float i_s = sigmoid_f(gi), f_s = sigmoid_f(gf);
      float g_t = tanh_f(gg), o_s = sigmoid_f(go);
      c_st = f_s * c_st + i_s * g_t;
      float h = o_s * tanh_f(c_st);
      // pack 4 cols into 8B via two shuffles; lanes j%4==0 store LLC-direct.
      // Ring store issued FIRST (oldest) so vmcnt(1) below waits only it.
      unsigned short hb = f2bf(h);
      unsigned other = __shfl_xor((unsigned)hb, 1);
      unsigned u = ((unsigned)hb & 0xffffu) | (other << 16);   // cols j, j+1
      unsigned u2 = __shfl_xor(u, 2);                          // cols j+2, j+3
      if ((j_l & 3) == 0) {
        ull_t v8 = (ull_t)u | ((ull_t)u2 << 32);
        ull_t* dst = (ull_t*)(ring_g + (size_t)t * SLOT_SHORTS +
                              b_l * 1024 + m * 16 + j_l);
        __hip_atomic_store(dst, v8, __ATOMIC_RELAXED, __HIP_MEMORY_SCOPE_AGENT);
      }
      asm volatile("" ::: "memory");   // keep out-store AFTER ring store
      out[((size_t)(g * 8 + b_l) * 512 + t) * 1024 + m * 16 + j_l] = h;
    }
    // drain the ring store only (oldest); out[] HBM ack stays off the path
    asm volatile("s_waitcnt vmcnt(1)" ::: "memory");
    __syncthreads();
    if (tid == 0)
      __hip_atomic_store(fl_g + m, (unsigned)(t + 1),
                         __ATOMIC_RELAXED, __HIP_MEMORY_SCOPE_AGENT);
  }
}

// ---------------------------------------------------------------- launcher
extern "C" void kernel_launch(void* const* d_in, const int* in_sizes, int n_in,
                              void* d_out, int out_size, void* d_ws, size_t ws_size,
                              hipStream_t stream) {
  const float* x    = (const float*)d_in[0];   // [32,512,1024]
  const float* wi   = (const float*)d_in[1];   // [1024,4096]
  const float* wh   = (const float*)d_in[2];   // [1024,4096]
  const float* bias = (const float*)d_in[3];   // [4096]
  float* out = (float*)d_out;

  char* ws = (char*)d_ws;
  unsigned short* xg   = (unsigned short*)(ws + XG_OFF);
  unsigned short* xb   = (unsigned short*)(ws + XB_OFF);   // dead after gemm_xg
  unsigned short* ring = (unsigned short*)(ws + RING_OFF); // overlays xb
  unsigned short* wiT  = (unsigned short*)(ws + WIT_OFF);
  unsigned short* whT  = (unsigned short*)(ws + WHT_OFF);
  unsigned* flags      = (unsigned*)(ws + FLAGS_OFF);

  conv_x_bf16<<<16384, 256, 0, stream>>>(x, xb);
  transpose_w_bf16<<<dim3(128, 32), dim3(32, 8), 0, stream>>>(wi, wiT);
  transpose_w_bf16<<<dim3(128, 32), dim3(32, 8), 0, stream>>>(wh, whT);
  init_ws<<<1, 256, 0, stream>>>(flags);
  gemm_xg<<<dim3(32, 128), 256, 34816, stream>>>(xb, wiT, xg);
  lstm_persistent<<<NBLK_B, 256, 0, stream>>>(xg, whT, bias, out, ring, flags);
}

// Round 9
// 2086.462 us; speedup vs baseline: 2.1790x; 1.0389x over previous
//
#include <hip/hip_runtime.h>

// ---------------------------------------------------------------------------
// ManualLSTM: B=32, S=512, H=1024.
//   Phase A: xg = bf16(x) @ bf16(Wi)  -> bf16 [16384][4096]  (bias in phase B)
//   Phase B (R15 = R10 protocol + 32 blocks/group, 2x work/block):
//     4 groups x 32 blocks (128 blocks). Group g owns batches 8g..8g+7 +
//     full gate dim; block m owns hidden cols m*32..+32 (128 gate cols).
//     - Wh B-frags pinned in VGPRs: 64 x bf16x8 = 256 VGPR (asm "+v" tie,
//       R10-validated technique). Wave wv = gate group; 2 N-tiles/wave.
//       K-loop: 32 ds_read_b128 (A, reused for both N-tiles) + 64 MFMA.
//     - h exchange via NEVER-REUSED ring (512 slots x 4 groups x 16KB,
//       overlays dead xb). Producers: shfl-packed 8B agent-scope atomic
//       stores. Consumers: ONE cooperative coalesced dwordx4 gather into
//       LDS + ds_read redistribution (R9/R10-validated; R13 proved per-wave
//       direct-reg loads storm the LLC).
//     - Flags at 16B stride (R14 proved 4B-packed flags cost ~235us via
//       LLC line contention). Poll: tid<32, 8 lines.
//     - Drain: ring store first, out[] second, vmcnt(1) waits only the ring
//       store; barrier; relaxed agent flag (R10-validated).
//     Rationale: halves sync participants (gather burst, poll fan-in,
//     producer flag stores) while doubling cheap, pipelined MFMA per block.
// ---------------------------------------------------------------------------

typedef __attribute__((ext_vector_type(4))) float f32x4_t;
typedef __attribute__((ext_vector_type(8))) short bf16x8_t;
typedef unsigned long long ull_t;

#define HID   1024
#define SLEN  512
#define NGATE 4096

// ws layout (bytes)
#define XG_OFF    0ULL                      // 16384*4096*2 = 134217728
#define RING_OFF  134217728ULL              // 512*4*16384  = 33554432 (old xb)
#define WIT_OFF   167772160ULL              // 4096*1024*2  = 8388608
#define WHT_OFF   176160768ULL              // 4096*1024*2  = 8388608
#define FLAGS_OFF 184680448ULL              // 128 flags * 16B stride = 2048B
#define XB_OFF    RING_OFF                  // xb dead after gemm_xg

#define NBLK_B      128                     // 4 groups x 32 blocks
#define FLAG_STRIDE 4                       // dwords (16B) -- R14: don't pack!
#define SLOT_SHORTS 32768                   // 4 groups * 8192 shorts = 64KB/slot

__device__ __forceinline__ unsigned short f2bf(float f) {
  unsigned u = __float_as_uint(f);
  u += 0x7fffu + ((u >> 16) & 1u);          // round-nearest-even
  return (unsigned short)(u >> 16);
}
__device__ __forceinline__ float bf2f(unsigned short u) {
  return __uint_as_float(((unsigned)u) << 16);
}
__device__ __forceinline__ float fast_rcp(float x) { return __builtin_amdgcn_rcpf(x); }
__device__ __forceinline__ float sigmoid_f(float x) { return fast_rcp(1.f + __expf(-x)); }
__device__ __forceinline__ float tanh_f(float x) { return 1.f - 2.f * fast_rcp(1.f + __expf(2.f * x)); }

// ---------------------------------------------------------------- converters
__global__ __launch_bounds__(256) void conv_x_bf16(const float* __restrict__ in,
                                                   unsigned short* __restrict__ out) {
  size_t i = (size_t)blockIdx.x * 256 + threadIdx.x;
  const float4* p = (const float4*)in;
  float4 v = p[i];
  ushort4 o;
  o.x = f2bf(v.x); o.y = f2bf(v.y); o.z = f2bf(v.z); o.w = f2bf(v.w);
  ((ushort4*)out)[i] = o;
}

// in: fp32 [1024][4096]  -> out: bf16 [4096][1024]  (out[n][k] = in[k][n])
__global__ void transpose_w_bf16(const float* __restrict__ in,
                                 unsigned short* __restrict__ out) {
  __shared__ float tile[32][33];
  int tx = threadIdx.x, ty = threadIdx.y;        // block (32, 8)
  int n0 = blockIdx.x * 32, k0 = blockIdx.y * 32;
  #pragma unroll
  for (int i = 0; i < 4; i++)
    tile[ty + 8 * i][tx] = in[(size_t)(k0 + ty + 8 * i) * NGATE + n0 + tx];
  __syncthreads();
  #pragma unroll
  for (int i = 0; i < 4; i++)
    out[(size_t)(n0 + ty + 8 * i) * HID + k0 + tx] = f2bf(tile[tx][ty + 8 * i]);
}

__global__ void init_ws(unsigned* __restrict__ flags) {
  int i = threadIdx.x;
  flags[i] = 0u;                            // 512 dwords (128 flags @16B)
  flags[i + 256] = 0u;
}

// ---------------------------------------------------------------- Phase A
// C[16384][4096] bf16 = A[16384][1024] bf16  x  BT[4096][1024] bf16
__global__ __launch_bounds__(256) void gemm_xg(const unsigned short* __restrict__ A,
                                               const unsigned short* __restrict__ BT,
                                               unsigned short* __restrict__ C) {
  extern __shared__ char smem[];
  char* As = smem;                 // 128 rows * 80B (32 bf16 + 16B pad)
  char* Bs = smem + 10240;
  const int tid = threadIdx.x;
  const int lane = tid & 63, w = tid >> 6, q = lane >> 4, l16 = lane & 15;
  const int wm = w & 1, wn = w >> 1;
  const size_t m0 = (size_t)blockIdx.y * 128, n0 = (size_t)blockIdx.x * 128;

  f32x4_t acc[4][4];
  #pragma unroll
  for (int i = 0; i < 4; i++)
    #pragma unroll
    for (int j = 0; j < 4; j++) acc[i][j] = (f32x4_t){0.f, 0.f, 0.f, 0.f};

  for (int kk = 0; kk < 32; kk++) {
    const int k0 = kk * 32;
    #pragma unroll
    for (int h = 0; h < 2; h++) {
      int idx = tid + h * 256;              // 0..511
      int r = idx >> 2, ch = idx & 3;
      uint4 va = *(const uint4*)((const char*)A + ((m0 + r) * HID + k0) * 2 + ch * 16);
      *(uint4*)(As + r * 80 + ch * 16) = va;
      uint4 vb = *(const uint4*)((const char*)BT + ((n0 + r) * HID + k0) * 2 + ch * 16);
      *(uint4*)(Bs + r * 80 + ch * 16) = vb;
    }
    __syncthreads();
    bf16x8_t af[4], bf[4];
    #pragma unroll
    for (int mt = 0; mt < 4; mt++)
      af[mt] = *(const bf16x8_t*)(As + (wm * 64 + mt * 16 + l16) * 80 + q * 16);
    #pragma unroll
    for (int nt = 0; nt < 4; nt++)
      bf[nt] = *(const bf16x8_t*)(Bs + (wn * 64 + nt * 16 + l16) * 80 + q * 16);
    #pragma unroll
    for (int mt = 0; mt < 4; mt++)
      #pragma unroll
      for (int nt = 0; nt < 4; nt++)
        acc[mt][nt] = __builtin_amdgcn_mfma_f32_16x16x32_bf16(af[mt], bf[nt], acc[mt][nt], 0, 0, 0);
    __syncthreads();
  }

  // epilogue: stage C tile (bf16 [128][136]) through LDS for coalesced stores
  unsigned short* cst = (unsigned short*)smem;
  #pragma unroll
  for (int mt = 0; mt < 4; mt++)
    #pragma unroll
    for (int nt = 0; nt < 4; nt++)
      #pragma unroll
      for (int r = 0; r < 4; r++) {
        int m = wm * 64 + mt * 16 + q * 4 + r;
        int n = wn * 64 + nt * 16 + l16;
        cst[m * 136 + n] = f2bf(acc[mt][nt][r]);
      }
  __syncthreads();
  #pragma unroll
  for (int i = 0; i < 8; i++) {
    int idx = tid + i * 256;                // < 2048
    int row = idx >> 4, ch = idx & 15;
    uint4 v = *(const uint4*)((const char*)cst + row * 272 + ch * 16);
    *(uint4*)((char*)C + ((m0 + row) * NGATE + n0) * 2 + ch * 16) = v;
  }
}

// ---------------------------------------------------------------- Phase B
// 4 groups x 32 blocks x 256 threads. Group = 8 batches, full gate dim.
// Block m: hidden cols m*32..+32 => gate cols G*1024 + m*32 + [0,32).
// Wave wv = gate group G; 2 N-tiles (nt=0,1) per wave.
__global__ __launch_bounds__(256, 1) void lstm_persistent(
    const unsigned short* __restrict__ xg,   // [16384][4096] bf16
    const unsigned short* __restrict__ whT,  // [4096][1024] bf16
    const float* __restrict__ bias,          // [4096]
    float* __restrict__ out,                 // [32][512][1024]
    unsigned short* ring,                    // 512 slots x 4 groups x [8][1024] bf16
    unsigned* flags) {                       // 128 @ 16B stride, group-major
  __shared__ __align__(16) char h_lds[8 * 2064];   // [8 rows b][2048B k] +16B pad
  __shared__ float gates[16 * 132];                // [16][4G*32 +pad] (rows 8-15 dup)

  const int tid = threadIdx.x;
  const int lane = tid & 63, wv = tid >> 6, q = lane >> 4, l16 = lane & 15;
  const int g = blockIdx.x >> 5;                   // group 0..3
  const int m = blockIdx.x & 31;                   // member 0..31
  const int b_l = tid >> 5, j_l = tid & 31;        // EW mapping (all 256)

  // pin Wh B-fragments in VGPRs: wave wv, N-tile nt covers gate col
  // wv*1024 + m*32 + nt*16 + l16; bfr[nt*32+kk] = frag kk. 256 VGPRs.
  // Volatile asm "+v" ties block load re-sinking (R8 failure; R10-validated).
  bf16x8_t bfr[64];
  {
    #pragma unroll
    for (int nt = 0; nt < 2; nt++) {
      const char* wrow = (const char*)whT +
          ((size_t)(wv * 1024 + m * 32 + nt * 16 + l16) * HID) * 2 + q * 16;
      #pragma unroll
      for (int kk = 0; kk < 32; kk++)
        bfr[nt * 32 + kk] = *(const bf16x8_t*)(wrow + kk * 64);
    }
    #pragma unroll
    for (int i = 0; i < 64; i++)
      asm volatile("" : "+v"(bfr[i]));
  }
  float bsr[4];
  #pragma unroll
  for (int G = 0; G < 4; G++) bsr[G] = bias[G * 1024 + m * 32 + j_l];
  float c_st = 0.f;
  const char* arow = h_lds + (l16 & 7) * 2064 + q * 16;   // rows 8-15 mirror 0-7
  unsigned short* ring_g = ring + (size_t)g * 8192;       // 16KB group image
  unsigned* fl_g = flags + g * 32 * FLAG_STRIDE;

  for (int t = 0; t < SLEN; t++) {
    // xg prefetch (no h dependency) — overlaps the flag wait
    unsigned short xgv[4];
    {
      const unsigned short* p =
          xg + ((size_t)(g * 8 + b_l) * 512 + t) * 4096 + m * 32 + j_l;
      xgv[0] = p[0]; xgv[1] = p[1024]; xgv[2] = p[2048]; xgv[3] = p[3072];
    }
    if (t > 0) {
      if (tid < 32) {
        const unsigned* fp = fl_g + tid * FLAG_STRIDE;
        while (__hip_atomic_load(fp, __ATOMIC_RELAXED, __HIP_MEMORY_SCOPE_AGENT) < (unsigned)t)
          __builtin_amdgcn_s_sleep(1);
      }
      __syncthreads();
      asm volatile("" ::: "memory");
      // gather group h image from ring slot t-1 with PLAIN coalesced dwordx4
      // (virgin addresses -> no stale L1/L2; producers wrote LLC)
      {
        const char* src = (const char*)(ring_g + (size_t)(t - 1) * SLOT_SHORTS);
        uint4 v0 = *(const uint4*)(src + tid * 16);
        uint4 v1 = *(const uint4*)(src + tid * 16 + 4096);
        uint4 v2 = *(const uint4*)(src + tid * 16 + 8192);
        uint4 v3 = *(const uint4*)(src + tid * 16 + 12288);
        int c0 = tid, c1 = tid + 256, c2 = tid + 512, c3 = tid + 768;
        *(uint4*)(h_lds + (c0 >> 7) * 2064 + (c0 & 127) * 16) = v0;
        *(uint4*)(h_lds + (c1 >> 7) * 2064 + (c1 & 127) * 16) = v1;
        *(uint4*)(h_lds + (c2 >> 7) * 2064 + (c2 & 127) * 16) = v2;
        *(uint4*)(h_lds + (c3 >> 7) * 2064 + (c3 & 127) * 16) = v3;
      }
    }
    __syncthreads();

    // K-loop: A-frag read once, used for BOTH N-tiles. 4 indep MFMA chains.
    f32x4_t a00 = (f32x4_t){0.f, 0.f, 0.f, 0.f};
    f32x4_t a01 = (f32x4_t){0.f, 0.f, 0.f, 0.f};
    f32x4_t a10 = (f32x4_t){0.f, 0.f, 0.f, 0.f};
    f32x4_t a11 = (f32x4_t){0.f, 0.f, 0.f, 0.f};
    if (t > 0) {
      #pragma unroll
      for (int kk = 0; kk < 32; kk += 2) {
        bf16x8_t x0 = *(const bf16x8_t*)(arow + kk * 64);
        bf16x8_t x1 = *(const bf16x8_t*)(arow + kk * 64 + 64);
        a00 = __builtin_amdgcn_mfma_f32_16x16x32_bf16(x0, bfr[kk], a00, 0, 0, 0);
        a10 = __builtin_amdgcn_mfma_f32_16x16x32_bf16(x0, bfr[32 + kk], a10, 0, 0, 0);
        a01 = __builtin_amdgcn_mfma_f32_16x16x32_bf16(x1, bfr[kk + 1], a01, 0, 0, 0);
        a11 = __builtin_amdgcn_mfma_f32_16x16x32_bf16(x1, bfr[32 + kk + 1], a11, 0, 0, 0);
      }
    }
    #pragma unroll
    for (int r = 0; r < 4; r++) {
      int bb = q * 4 + r;                          // rows 8-15 are duplicates
      gates[bb * 132 + wv * 32 + l16]      = a00[r] + a01[r];
      gates[bb * 132 + wv * 32 + 16 + l16] = a10[r] + a11[r];
    }
    __syncthreads();

    // elementwise: ALL 256 threads own (b_l, j_l), j_l in [0,32)
    {
      float gi = gates[b_l * 132 + j_l]      + bsr[0] + bf2f(xgv[0]);
      float gf = gates[b_l * 132 + 32 + j_l] + bsr[1] + bf2f(xgv[1]);
      float gg = gates[b_l * 132 + 64 + j_l] + bsr[2] + bf2f(xgv[2]);
      float go = gates[b_l * 132 + 96 + j_l] + bsr[3] + bf2f(xgv[3]);
      float i_s = sigmoid_f(gi), f_s = sigmoid_f(gf);
      float g_t = tanh_f(gg), o_s = sigmoid_f(go);
      c_st = f_s * c_st + i_s * g_t;
      float h = o_s * tanh_f(c_st);
      // pack 4 cols into 8B via two shuffles; lanes j%4==0 store LLC-direct.
      // Ring store issued FIRST (oldest) so vmcnt(1) below waits only it.
      unsigned short hb = f2bf(h);
      unsigned other = __shfl_xor((unsigned)hb, 1);
      unsigned u = ((unsigned)hb & 0xffffu) | (other << 16);   // cols j, j+1
      unsigned u2 = __shfl_xor(u, 2);                          // cols j+2, j+3
      if ((j_l & 3) == 0) {
        ull_t v8 = (ull_t)u | ((ull_t)u2 << 32);
        ull_t* dst = (ull_t*)(ring_g + (size_t)t * SLOT_SHORTS +
                              b_l * 1024 + m * 32 + j_l);
        __hip_atomic_store(dst, v8, __ATOMIC_RELAXED, __HIP_MEMORY_SCOPE_AGENT);
      }
      asm volatile("" ::: "memory");   // keep out-store AFTER ring store
      out[((size_t)(g * 8 + b_l) * 512 + t) * 1024 + m * 32 + j_l] = h;
    }
    // drain the ring store only (oldest); out[] HBM ack stays off the path
    asm volatile("s_waitcnt vmcnt(1)" ::: "memory");
    __syncthreads();
    if (tid == 0)
      __hip_atomic_store(fl_g + m * FLAG_STRIDE, (unsigned)(t + 1),
                         __ATOMIC_RELAXED, __HIP_MEMORY_SCOPE_AGENT);
  }
}

// ---------------------------------------------------------------- launcher
extern "C" void kernel_launch(void* const* d_in, const int* in_sizes, int n_in,
                              void* d_out, int out_size, void* d_ws, size_t ws_size,
                              hipStream_t stream) {
  const float* x    = (const float*)d_in[0];   // [32,512,1024]
  const float* wi   = (const float*)d_in[1];   // [1024,4096]
  const float* wh   = (const float*)d_in[2];   // [1024,4096]
  const float* bias = (const float*)d_in[3];   // [4096]
  float* out = (float*)d_out;

  char* ws = (char*)d_ws;
  unsigned short* xg   = (unsigned short*)(ws + XG_OFF);
  unsigned short* xb   = (unsigned short*)(ws + XB_OFF);   // dead after gemm_xg
  unsigned short* ring = (unsigned short*)(ws + RING_OFF); // overlays xb
  unsigned short* wiT  = (unsigned short*)(ws + WIT_OFF);
  unsigned short* whT  = (unsigned short*)(ws + WHT_OFF);
  unsigned* flags      = (unsigned*)(ws + FLAGS_OFF);

  conv_x_bf16<<<16384, 256, 0, stream>>>(x, xb);
  transpose_w_bf16<<<dim3(128, 32), dim3(32, 8), 0, stream>>>(wi, wiT);
  transpose_w_bf16<<<dim3(128, 32), dim3(32, 8), 0, stream>>>(wh, whT);
  init_ws<<<1, 256, 0, stream>>>(flags);
  gemm_xg<<<dim3(32, 128), 256, 34816, stream>>>(xb, wiT, xg);
  lstm_persistent<<<NBLK_B, 256, 0, stream>>>(xg, whT, bias, out, ring, flags);
}